// Round 11
// baseline (91.543 us; speedup 1.0000x reference)
//
#include <hip/hip_runtime.h>

typedef unsigned short u16;
typedef __attribute__((ext_vector_type(8))) short bf16x8;
typedef __attribute__((ext_vector_type(4))) float f32x4;
typedef __attribute__((ext_vector_type(8))) unsigned short u16x8;
typedef __attribute__((ext_vector_type(4))) unsigned short u16x4;
typedef __attribute__((ext_vector_type(2))) unsigned short u16x2;

// ---- bf16 helpers (RNE) ----
__device__ __forceinline__ u16 f2b(float f) {
  unsigned u = __builtin_bit_cast(unsigned, f);
  unsigned r = (u + 0x7fffu + ((u >> 16) & 1u)) >> 16;
  return (u16)r;
}
__device__ __forceinline__ float b2f(u16 u) {
  return __builtin_bit_cast(float, ((unsigned)u) << 16);
}
__device__ __forceinline__ void gload16(const void* g, void* l) {
  __builtin_amdgcn_global_load_lds(
      (const __attribute__((address_space(1))) unsigned int*)g,
      (__attribute__((address_space(3))) unsigned int*)l, 16, 0, 0);
}

// ---- fused prep: x cast (2048) | waT (1536) | wpT (1024) | rope tab (256) ----
__global__ __launch_bounds__(256) void k_prep(const float* __restrict__ x,
                                              const float* __restrict__ wa,
                                              const float* __restrict__ wp,
                                              u16* __restrict__ xb,
                                              u16* __restrict__ waT,
                                              u16* __restrict__ wpT,
                                              float2* __restrict__ tab) {
  __shared__ float t[32][33];
  const int idx = blockIdx.x;
  const int tid = threadIdx.x;
  if (idx < 2048) {                       // cast x -> bf16, 8 elems/thread
    int i = idx * 256 + tid;
    float4 v0 = ((const float4*)x)[i * 2];
    float4 v1 = ((const float4*)x)[i * 2 + 1];
    u16x8 o;
    o[0] = f2b(v0.x); o[1] = f2b(v0.y); o[2] = f2b(v0.z); o[3] = f2b(v0.w);
    o[4] = f2b(v1.x); o[5] = f2b(v1.y); o[6] = f2b(v1.z); o[7] = f2b(v1.w);
    ((u16x8*)xb)[i] = o;
    return;
  }
  const int tx = tid & 31, ty = tid >> 5; // transpose tiles, block as (32,8)
  if (idx < 3584) {                       // waT: (1024 x 1536) -> (1536 x 1024)
    int tt = idx - 2048;
    int c0 = (tt % 48) * 32, r0 = (tt / 48) * 32;
    for (int ii = 0; ii < 4; ++ii)
      t[ty + ii * 8][tx] = wa[(size_t)(r0 + ty + ii * 8) * 1536 + c0 + tx];
    __syncthreads();
    for (int ii = 0; ii < 4; ++ii)
      waT[(size_t)(c0 + ty + ii * 8) * 1024 + r0 + tx] = f2b(t[tx][ty + ii * 8]);
    return;
  }
  if (idx < 4608) {                       // wpT: (1024 x 1024) -> (1024 x 1024)
    int tt = idx - 3584;
    int c0 = (tt & 31) * 32, r0 = (tt >> 5) * 32;
    for (int ii = 0; ii < 4; ++ii)
      t[ty + ii * 8][tx] = wp[(size_t)(r0 + ty + ii * 8) * 1024 + c0 + tx];
    __syncthreads();
    for (int ii = 0; ii < 4; ++ii)
      wpT[(size_t)(c0 + ty + ii * 8) * 1024 + r0 + tx] = f2b(t[tx][ty + ii * 8]);
    return;
  }
  {                                       // rope table
    int e = (idx - 4608) * 256 + tid;     // 65536 entries
    int tt = e >> 5, i = e & 31;
    float inv = expf((float)(2 * i) * -0.14391156831f);
    float fr = (float)tt * inv;
    float s, c;
    sincosf(fr, &s, &c);
    tab[tt * 32 + i] = make_float2(c, s);
  }
}

// ---- GEMM1 + fused rope/rms/V-transpose epilogue ----
__global__ __launch_bounds__(256) void k_gemm1(const u16* __restrict__ A,
                                               const u16* __restrict__ Bt,
                                               const float2* __restrict__ tab,
                                               u16* __restrict__ Qb,
                                               u16* __restrict__ Kb,
                                               u16* __restrict__ Vtb) {
  __shared__ u16 smem[64 * 64 + 128 * 64];   // lA | lB; reused as vbuf
  u16* lA = smem;
  u16* lB = smem + 64 * 64;
  const int tid = threadIdx.x;
  const int lane = tid & 63, w = tid >> 6;
  const int wr = w >> 1, wc = w & 1;
  const int la = lane & 15, hi = lane >> 4;
  const int bx = blockIdx.x;
  const int bm0 = blockIdx.y * 64, bn0 = bx * 128;
  const int K = 1024;
  const f32x4 zero = {0.f, 0.f, 0.f, 0.f};
  f32x4 acc[2][4];
#pragma unroll
  for (int m = 0; m < 2; ++m)
#pragma unroll
    for (int n = 0; n < 4; ++n) acc[m][n] = zero;

  const int r = tid >> 3;
  const int s = tid & 7;
  for (int k0 = 0; k0 < K; k0 += 64) {
#pragma unroll
    for (int rr = 0; rr < 2; ++rr) {
      int row = rr * 32 + r;
      gload16(A + (size_t)(bm0 + row) * K + k0 + ((s ^ (row & 7)) << 3),
              &lA[(rr * 256 + tid) * 8]);
    }
#pragma unroll
    for (int rr = 0; rr < 4; ++rr) {
      int row = rr * 32 + r;
      gload16(Bt + (size_t)(bn0 + row) * K + k0 + ((s ^ (row & 7)) << 3),
              &lB[(rr * 256 + tid) * 8]);
    }
    __syncthreads();
#pragma unroll
    for (int kk = 0; kk < 2; ++kk) {
      bf16x8 af[2], bfr[4];
#pragma unroll
      for (int m = 0; m < 2; ++m) {
        int R = wr * 32 + m * 16 + la;
        af[m] = *(const bf16x8*)&lA[R * 64 + (((kk * 4 + hi) ^ (R & 7)) << 3)];
      }
#pragma unroll
      for (int n = 0; n < 4; ++n) {
        int R = wc * 64 + n * 16 + la;
        bfr[n] = *(const bf16x8*)&lB[R * 64 + (((kk * 4 + hi) ^ (R & 7)) << 3)];
      }
#pragma unroll
      for (int m = 0; m < 2; ++m)
#pragma unroll
        for (int n = 0; n < 4; ++n)
          acc[m][n] = __builtin_amdgcn_mfma_f32_16x16x32_bf16(af[m], bfr[n], acc[m][n], 0, 0, 0);
    }
    __syncthreads();
  }
  // ---- fused epilogue ----
  const int tloc = bm0 & 2047;
  const int bb = bm0 >> 11;
  if (bx < 10) {
    const int isq = (bx < 8);
    const int head = isq ? (2 * bx + wc) : (2 * (bx - 8) + wc);
    u16* outp = isq ? Qb : Kb;
    const size_t hbase = ((size_t)(bb * (isq ? 16 : 4) + head) * 2048) * 64;
    const int odd = la & 1;
#pragma unroll
    for (int m = 0; m < 2; ++m)
#pragma unroll
      for (int j = 0; j < 4; ++j) {
        const int tr = tloc + wr * 32 + m * 16 + hi * 4 + j;
        const float2* tb = tab + tr * 32 + (la >> 1);
        float y[4], ssl = 0.f;
#pragma unroll
        for (int n = 0; n < 4; ++n) {
          float v = acc[m][n][j];
          float p = __shfl_xor(v, 1);
          float2 cs = tb[n * 8];
          y[n] = odd ? fmaf(v, cs.x, p * cs.y)
                     : fmaf(v, cs.x, -p * cs.y);
          ssl = fmaf(y[n], y[n], ssl);
        }
        ssl += __shfl_xor(ssl, 1);
        ssl += __shfl_xor(ssl, 2);
        ssl += __shfl_xor(ssl, 4);
        ssl += __shfl_xor(ssl, 8);
        const float sc = rsqrtf(ssl * (1.0f / 64.0f) + 1e-6f);
        u16* rp = outp + hbase + (size_t)tr * 64 + la;
#pragma unroll
        for (int n = 0; n < 4; ++n) rp[n * 16] = f2b(y[n] * sc);
      }
  } else {
    // V block: bf16 into vbuf[64][132] (reuses lA/lB), transposed write
    u16* vbuf = smem;
#pragma unroll
    for (int m = 0; m < 2; ++m)
#pragma unroll
      for (int n = 0; n < 4; ++n)
#pragma unroll
        for (int j = 0; j < 4; ++j)
          vbuf[(wr * 32 + m * 16 + hi * 4 + j) * 132 + wc * 64 + n * 16 + la] =
              f2b(acc[m][n][j]);
    __syncthreads();
    const int dloc = tid >> 1, th = tid & 1;
    const int g = 2 * (bx - 10) + (dloc >> 6);
    const int d = dloc & 63;
    u16* dst = Vtb + ((size_t)(bb * 4 + g) * 64 + d) * 2048 + tloc + th * 32;
#pragma unroll
    for (int c = 0; c < 4; ++c) {
      u16x8 o;
#pragma unroll
      for (int e = 0; e < 8; ++e) o[e] = vbuf[(th * 32 + c * 8 + e) * 132 + dloc];
      *(u16x8*)(dst + c * 8) = o;
    }
  }
}

// ---- GEMM2: C[M,N] f32 = A[M,K](bf16) * Bt[N,K](bf16) ----
template<int OUT_BF16>
__global__ __launch_bounds__(256) void k_gemm_bt(const u16* __restrict__ A,
                                                 const u16* __restrict__ Bt,
                                                 void* __restrict__ Cv,
                                                 int M, int N, int K) {
  __shared__ u16 lA[64 * 64];
  __shared__ u16 lB[128 * 64];
  const int tid = threadIdx.x;
  const int lane = tid & 63, w = tid >> 6;
  const int wr = w >> 1, wc = w & 1;
  const int la = lane & 15, hi = lane >> 4;
  const int bm0 = blockIdx.y * 64, bn0 = blockIdx.x * 128;
  const f32x4 zero = {0.f, 0.f, 0.f, 0.f};
  f32x4 acc[2][4];
#pragma unroll
  for (int m = 0; m < 2; ++m)
#pragma unroll
    for (int n = 0; n < 4; ++n) acc[m][n] = zero;

  const int r = tid >> 3;
  const int s = tid & 7;
  for (int k0 = 0; k0 < K; k0 += 64) {
#pragma unroll
    for (int rr = 0; rr < 2; ++rr) {
      int row = rr * 32 + r;
      gload16(A + (size_t)(bm0 + row) * K + k0 + ((s ^ (row & 7)) << 3),
              &lA[(rr * 256 + tid) * 8]);
    }
#pragma unroll
    for (int rr = 0; rr < 4; ++rr) {
      int row = rr * 32 + r;
      gload16(Bt + (size_t)(bn0 + row) * K + k0 + ((s ^ (row & 7)) << 3),
              &lB[(rr * 256 + tid) * 8]);
    }
    __syncthreads();
#pragma unroll
    for (int kk = 0; kk < 2; ++kk) {
      bf16x8 af[2], bfr[4];
#pragma unroll
      for (int m = 0; m < 2; ++m) {
        int R = wr * 32 + m * 16 + la;
        af[m] = *(const bf16x8*)&lA[R * 64 + (((kk * 4 + hi) ^ (R & 7)) << 3)];
      }
#pragma unroll
      for (int n = 0; n < 4; ++n) {
        int R = wc * 64 + n * 16 + la;
        bfr[n] = *(const bf16x8*)&lB[R * 64 + (((kk * 4 + hi) ^ (R & 7)) << 3)];
      }
#pragma unroll
      for (int m = 0; m < 2; ++m)
#pragma unroll
        for (int n = 0; n < 4; ++n)
          acc[m][n] = __builtin_amdgcn_mfma_f32_16x16x32_bf16(af[m], bfr[n], acc[m][n], 0, 0, 0);
    }
    __syncthreads();
  }
  float* Cf = (float*)Cv;
  u16*   Cb = (u16*)Cv;
#pragma unroll
  for (int m = 0; m < 2; ++m)
#pragma unroll
    for (int n = 0; n < 4; ++n)
#pragma unroll
      for (int j = 0; j < 4; ++j) {
        int row = bm0 + wr * 32 + m * 16 + hi * 4 + j;
        int col = bn0 + wc * 64 + n * 16 + la;
        float v = acc[m][n][j];
        if (OUT_BF16) Cb[(size_t)row * N + col] = f2b(v);
        else          Cf[(size_t)row * N + col] = v;
      }
}

// ---- causal GQA flash attention, v8.1: 32 q-rows/wave (mask fixed) ----
// grid (32 bh, 16 qtiles of 128 rows), block 256 (4 waves x 32 q-rows).
// Each wave: 2 sequential 16-q subtiles vs the shared K/V tile; K and V
// fragments cached in REGISTERS across both subtiles. Mask threshold is
// tile-local: qglobal - kv0 == (w*32 + s2*16 + la) & 63 for the wave's
// last tile (NO 64-bias -- that was the v8 bug).
__global__ __launch_bounds__(256, 2) void k_attn(const u16* __restrict__ Qb,
                                                 const u16* __restrict__ Kb,
                                                 const u16* __restrict__ Vtb,
                                                 u16* __restrict__ Ob) {
  __shared__ u16 lK[2][64][64];
  __shared__ u16 lVt[2][64][64];
  __shared__ u16 lP[4][16][64];
  const int bh = blockIdx.x;
  const int b = bh >> 4, h = bh & 15, g = h >> 2;
  const int y = blockIdx.y;
  const int qtile = (y < 8) ? (15 - y) : (y - 8);   // heavy batch first
  const int tid = threadIdx.x;
  const int lane = tid & 63, w = tid >> 6;
  const int la = lane & 15, hi = lane >> 4;
  const int qr0 = qtile * 128 + w * 32;             // wave's first q row
  const int nt = 2 * qtile + 2;
  const int ktmax_w = (qr0 + 31) >> 6;              // wave's last tile

  const u16* Qg  = Qb  + (size_t)(b * 16 + h) * 2048 * 64;
  const u16* Kg  = Kb  + (size_t)(b * 4 + g) * 2048 * 64;
  const u16* Vtg = Vtb + (size_t)(b * 4 + g) * 64 * 2048;

  // Q fragments for both 16-q subtiles (loop-invariant)
  bf16x8 qf[2][2];
#pragma unroll
  for (int s2 = 0; s2 < 2; ++s2) {
    const u16* ptr = Qg + (size_t)(qr0 + s2 * 16 + la) * 64 + hi * 8;
    qf[s2][0] = *(const bf16x8*)ptr;
    qf[s2][1] = *(const bf16x8*)(ptr + 32);
  }
  const float C = 0.18033688011f;      // 0.125 * log2(e)
  const float nmc = -64.0f * C;        // fixed max (|q|=|k|=8 after RMS)
  float l0 = 0.f, l1 = 0.f;
  const f32x4 zero = {0.f, 0.f, 0.f, 0.f};
  f32x4 ao0[4], ao1[4];
#pragma unroll
  for (int f = 0; f < 4; ++f) { ao0[f] = zero; ao1[f] = zero; }

  const int sr = tid >> 3;             // staging row 0..31 (and +32)
  const int ss = (tid & 7) * 8;
  const int sw = ss ^ ((sr & 7) << 3);
  const int rcc = (hi * 8) ^ ((la & 7) << 3);

  {                                    // prologue: stage tile 0
    u16x8 k0 = *(const u16x8*)(Kg  + (size_t)sr * 64 + ss);
    u16x8 k1 = *(const u16x8*)(Kg  + (size_t)(sr + 32) * 64 + ss);
    u16x8 q0 = *(const u16x8*)(Vtg + (size_t)sr * 2048 + ss);
    u16x8 q1 = *(const u16x8*)(Vtg + (size_t)(sr + 32) * 2048 + ss);
    *(u16x8*)(&lK[0][sr][sw])       = k0;
    *(u16x8*)(&lK[0][sr + 32][sw])  = k1;
    *(u16x8*)(&lVt[0][sr][sw])      = q0;
    *(u16x8*)(&lVt[0][sr + 32][sw]) = q1;
  }

  for (int kt = 0; kt < nt; ++kt) {
    const int cur = kt & 1;
    __syncthreads();                   // buf[cur] ready (written last iter)

    // prefetch next tile (issued after barrier; drains at trailing ds_write)
    u16x8 kreg0, kreg1, vreg0, vreg1;
    if (kt + 1 < nt) {
      int kv = (kt + 1) * 64;
      kreg0 = *(const u16x8*)(Kg  + (size_t)(kv + sr) * 64 + ss);
      kreg1 = *(const u16x8*)(Kg  + (size_t)(kv + sr + 32) * 64 + ss);
      vreg0 = *(const u16x8*)(Vtg + (size_t)sr * 2048 + kv + ss);
      vreg1 = *(const u16x8*)(Vtg + (size_t)(sr + 32) * 2048 + kv + ss);
    }

    if (kt <= ktmax_w) {
      // load K and V fragments ONCE (reused by both q-subtiles)
      bf16x8 kb[4][2], vb[4][2];
#pragma unroll
      for (int n = 0; n < 4; ++n) {
        const u16* kr = &lK[cur][n * 16 + la][0];
        kb[n][0] = *(const bf16x8*)(kr + rcc);
        kb[n][1] = *(const bf16x8*)(kr + (rcc ^ 32));
        const u16* vr = &lVt[cur][n * 16 + la][0];
        vb[n][0] = *(const bf16x8*)(vr + rcc);
        vb[n][1] = *(const bf16x8*)(vr + (rcc ^ 32));
      }
      const int domask = (kt == ktmax_w);
#pragma unroll
      for (int s2 = 0; s2 < 2; ++s2) {
        float z_[4][4];
        __builtin_amdgcn_s_setprio(1);
#pragma unroll
        for (int n = 0; n < 4; ++n) {
          f32x4 z = zero;
          z = __builtin_amdgcn_mfma_f32_16x16x32_bf16(kb[n][0], qf[s2][0], z, 0, 0, 0);
          z = __builtin_amdgcn_mfma_f32_16x16x32_bf16(kb[n][1], qf[s2][1], z, 0, 0, 0);
#pragma unroll
          for (int j = 0; j < 4; ++j) z_[n][j] = z[j];
        }
        __builtin_amdgcn_s_setprio(0);
        if (domask) {                  // causal mask, tile-local coords
          const int qrow = (w * 32 + s2 * 16 + la) & 63;
#pragma unroll
          for (int n = 0; n < 4; ++n)
#pragma unroll
            for (int j = 0; j < 4; ++j)
              if (n * 16 + hi * 4 + j > qrow) z_[n][j] = -3e38f;
        }
        float rs = 0.f;
#pragma unroll
        for (int n = 0; n < 4; ++n)
#pragma unroll
          for (int j = 0; j < 4; ++j) {
            float pe = __builtin_amdgcn_exp2f(fmaf(z_[n][j], C, nmc));
            z_[n][j] = pe;
            rs += pe;
          }
        if (s2 == 0) l0 += rs; else l1 += rs;
        // pack P -> bf16, store to per-wave LDS slice (in-wave RAW ordered)
#pragma unroll
        for (int n = 0; n < 4; ++n) {
          unsigned w0, w1;
          asm("v_cvt_pk_bf16_f32 %0, %1, %2" : "=v"(w0) : "v"(z_[n][0]), "v"(z_[n][1]));
          asm("v_cvt_pk_bf16_f32 %0, %1, %2" : "=v"(w1) : "v"(z_[n][2]), "v"(z_[n][3]));
          uint2 pw; pw.x = w0; pw.y = w1;
          *(uint2*)(&lP[w][la][(n * 16 + hi * 4) ^ ((la & 7) << 3)]) = pw;
        }
        {
          const u16* pr = &lP[w][la][0];
          bf16x8 pa0 = *(const bf16x8*)(pr + rcc);
          bf16x8 pa1 = *(const bf16x8*)(pr + (rcc ^ 32));
          __builtin_amdgcn_s_setprio(1);
#pragma unroll
          for (int f = 0; f < 4; ++f) {
            if (s2 == 0) {
              ao0[f] = __builtin_amdgcn_mfma_f32_16x16x32_bf16(pa0, vb[f][0], ao0[f], 0, 0, 0);
              ao0[f] = __builtin_amdgcn_mfma_f32_16x16x32_bf16(pa1, vb[f][1], ao0[f], 0, 0, 0);
            } else {
              ao1[f] = __builtin_amdgcn_mfma_f32_16x16x32_bf16(pa0, vb[f][0], ao1[f], 0, 0, 0);
              ao1[f] = __builtin_amdgcn_mfma_f32_16x16x32_bf16(pa1, vb[f][1], ao1[f], 0, 0, 0);
            }
          }
          __builtin_amdgcn_s_setprio(0);
        }
      }
    }
    if (kt + 1 < nt) {                 // write next tile into other buffer
      const int nxt = cur ^ 1;
      *(u16x8*)(&lK[nxt][sr][sw])       = kreg0;
      *(u16x8*)(&lK[nxt][sr + 32][sw])  = kreg1;
      *(u16x8*)(&lVt[nxt][sr][sw])      = vreg0;
      *(u16x8*)(&lVt[nxt][sr + 32][sw]) = vreg1;
    }
  }
  // epilogue: reduce l across hi-copies once, then normalize + store
  l0 += __shfl_xor(l0, 16, 64);
  l0 += __shfl_xor(l0, 32, 64);
  l1 += __shfl_xor(l1, 16, 64);
  l1 += __shfl_xor(l1, 32, 64);
#pragma unroll
  for (int s2 = 0; s2 < 2; ++s2) {
    float lv = (s2 == 0) ? l0 : l1;
    float linv[4];
#pragma unroll
    for (int j = 0; j < 4; ++j) linv[j] = 1.0f / __shfl(lv, 4 * hi + j, 64);
#pragma unroll
    for (int f = 0; f < 4; ++f)
#pragma unroll
      for (int j = 0; j < 4; ++j) {
        int row = qr0 + s2 * 16 + hi * 4 + j;
        float v = ((s2 == 0) ? ao0[f][j] : ao1[f][j]) * linv[j];
        Ob[((size_t)(b * 2048 + row)) * 1024 + h * 64 + f * 16 + la] = f2b(v);
      }
  }
}

extern "C" void kernel_launch(void* const* d_in, const int* in_sizes, int n_in,
                              void* d_out, int out_size, void* d_ws, size_t ws_size,
                              hipStream_t stream) {
  const float* x  = (const float*)d_in[0];   // (2,2048,1024) f32
  const float* wa = (const float*)d_in[1];   // (1024,1536)  f32
  const float* wp = (const float*)d_in[2];   // (1024,1024)  f32
  float* out = (float*)d_out;                // (2,2048,1024) f32
  char* ws = (char*)d_ws;
  u16* xb    = (u16*)(ws + 0);          // 4096x1024 bf16
  u16* waT   = (u16*)(ws + 8388608);    // 1536x1024 bf16
  u16* wpT   = (u16*)(ws + 11534336);   // 1024x1024 bf16
  u16* Qb    = (u16*)(ws + 26214400);   // [2][16][2048][64] bf16
  u16* Kb    = (u16*)(ws + 34603008);   // [2][4][2048][64] bf16
  u16* Vtb   = (u16*)(ws + 36700160);   // [2][4][64][2048] bf16
  u16* Ob    = (u16*)(ws + 38797312);   // 4096x1024 bf16
  float2* rt = (float2*)(ws + 47185920); // 2048x32 float2 (512KB)

  k_prep<<<4864, 256, 0, stream>>>(x, wa, wp, xb, waT, wpT, rt);
  k_gemm1<<<dim3(12, 64), 256, 0, stream>>>(xb, waT, rt, Qb, Kb, Vtb);
  k_attn<<<dim3(32, 16), 256, 0, stream>>>(Qb, Kb, Vtb, Ob);
  k_gemm_bt<0><<<dim3(8, 64), 256, 0, stream>>>(Ob, wpT, out, 4096, 1024, 1024);
}

// Round 12
// 82.598 us; speedup vs baseline: 1.1083x; 1.1083x over previous
//
#include <hip/hip_runtime.h>

typedef unsigned short u16;
typedef __attribute__((ext_vector_type(8))) short bf16x8;
typedef __attribute__((ext_vector_type(4))) float f32x4;
typedef __attribute__((ext_vector_type(8))) unsigned short u16x8;
typedef __attribute__((ext_vector_type(4))) unsigned short u16x4;
typedef __attribute__((ext_vector_type(2))) unsigned short u16x2;

// ---- bf16 helpers (RNE) ----
__device__ __forceinline__ u16 f2b(float f) {
  unsigned u = __builtin_bit_cast(unsigned, f);
  unsigned r = (u + 0x7fffu + ((u >> 16) & 1u)) >> 16;
  return (u16)r;
}
__device__ __forceinline__ float b2f(u16 u) {
  return __builtin_bit_cast(float, ((unsigned)u) << 16);
}
__device__ __forceinline__ void gload16(const void* g, void* l) {
  __builtin_amdgcn_global_load_lds(
      (const __attribute__((address_space(1))) unsigned int*)g,
      (__attribute__((address_space(3))) unsigned int*)l, 16, 0, 0);
}

// ---- fused prep: x cast (2048) | waT (1536) | wpT (1024) | rope tab (256) ----
__global__ __launch_bounds__(256) void k_prep(const float* __restrict__ x,
                                              const float* __restrict__ wa,
                                              const float* __restrict__ wp,
                                              u16* __restrict__ xb,
                                              u16* __restrict__ waT,
                                              u16* __restrict__ wpT,
                                              float2* __restrict__ tab) {
  __shared__ float t[32][33];
  const int idx = blockIdx.x;
  const int tid = threadIdx.x;
  if (idx < 2048) {                       // cast x -> bf16, 8 elems/thread
    int i = idx * 256 + tid;
    float4 v0 = ((const float4*)x)[i * 2];
    float4 v1 = ((const float4*)x)[i * 2 + 1];
    u16x8 o;
    o[0] = f2b(v0.x); o[1] = f2b(v0.y); o[2] = f2b(v0.z); o[3] = f2b(v0.w);
    o[4] = f2b(v1.x); o[5] = f2b(v1.y); o[6] = f2b(v1.z); o[7] = f2b(v1.w);
    ((u16x8*)xb)[i] = o;
    return;
  }
  const int tx = tid & 31, ty = tid >> 5; // transpose tiles, block as (32,8)
  if (idx < 3584) {                       // waT: (1024 x 1536) -> (1536 x 1024)
    int tt = idx - 2048;
    int c0 = (tt % 48) * 32, r0 = (tt / 48) * 32;
    for (int ii = 0; ii < 4; ++ii)
      t[ty + ii * 8][tx] = wa[(size_t)(r0 + ty + ii * 8) * 1536 + c0 + tx];
    __syncthreads();
    for (int ii = 0; ii < 4; ++ii)
      waT[(size_t)(c0 + ty + ii * 8) * 1024 + r0 + tx] = f2b(t[tx][ty + ii * 8]);
    return;
  }
  if (idx < 4608) {                       // wpT: (1024 x 1024) -> (1024 x 1024)
    int tt = idx - 3584;
    int c0 = (tt & 31) * 32, r0 = (tt >> 5) * 32;
    for (int ii = 0; ii < 4; ++ii)
      t[ty + ii * 8][tx] = wp[(size_t)(r0 + ty + ii * 8) * 1024 + c0 + tx];
    __syncthreads();
    for (int ii = 0; ii < 4; ++ii)
      wpT[(size_t)(c0 + ty + ii * 8) * 1024 + r0 + tx] = f2b(t[tx][ty + ii * 8]);
    return;
  }
  {                                       // rope table
    int e = (idx - 4608) * 256 + tid;     // 65536 entries
    int tt = e >> 5, i = e & 31;
    float inv = expf((float)(2 * i) * -0.14391156831f);
    float fr = (float)tt * inv;
    float s, c;
    sincosf(fr, &s, &c);
    tab[tt * 32 + i] = make_float2(c, s);
  }
}

// ---- GEMM1 + fused rope/rms/V-transpose epilogue ----
__global__ __launch_bounds__(256) void k_gemm1(const u16* __restrict__ A,
                                               const u16* __restrict__ Bt,
                                               const float2* __restrict__ tab,
                                               u16* __restrict__ Qb,
                                               u16* __restrict__ Kb,
                                               u16* __restrict__ Vtb) {
  __shared__ u16 smem[64 * 64 + 128 * 64];   // lA | lB; reused as vbuf
  u16* lA = smem;
  u16* lB = smem + 64 * 64;
  const int tid = threadIdx.x;
  const int lane = tid & 63, w = tid >> 6;
  const int wr = w >> 1, wc = w & 1;
  const int la = lane & 15, hi = lane >> 4;
  const int bx = blockIdx.x;
  const int bm0 = blockIdx.y * 64, bn0 = bx * 128;
  const int K = 1024;
  const f32x4 zero = {0.f, 0.f, 0.f, 0.f};
  f32x4 acc[2][4];
#pragma unroll
  for (int m = 0; m < 2; ++m)
#pragma unroll
    for (int n = 0; n < 4; ++n) acc[m][n] = zero;

  const int r = tid >> 3;
  const int s = tid & 7;
  for (int k0 = 0; k0 < K; k0 += 64) {
#pragma unroll
    for (int rr = 0; rr < 2; ++rr) {
      int row = rr * 32 + r;
      gload16(A + (size_t)(bm0 + row) * K + k0 + ((s ^ (row & 7)) << 3),
              &lA[(rr * 256 + tid) * 8]);
    }
#pragma unroll
    for (int rr = 0; rr < 4; ++rr) {
      int row = rr * 32 + r;
      gload16(Bt + (size_t)(bn0 + row) * K + k0 + ((s ^ (row & 7)) << 3),
              &lB[(rr * 256 + tid) * 8]);
    }
    __syncthreads();
#pragma unroll
    for (int kk = 0; kk < 2; ++kk) {
      bf16x8 af[2], bfr[4];
#pragma unroll
      for (int m = 0; m < 2; ++m) {
        int R = wr * 32 + m * 16 + la;
        af[m] = *(const bf16x8*)&lA[R * 64 + (((kk * 4 + hi) ^ (R & 7)) << 3)];
      }
#pragma unroll
      for (int n = 0; n < 4; ++n) {
        int R = wc * 64 + n * 16 + la;
        bfr[n] = *(const bf16x8*)&lB[R * 64 + (((kk * 4 + hi) ^ (R & 7)) << 3)];
      }
#pragma unroll
      for (int m = 0; m < 2; ++m)
#pragma unroll
        for (int n = 0; n < 4; ++n)
          acc[m][n] = __builtin_amdgcn_mfma_f32_16x16x32_bf16(af[m], bfr[n], acc[m][n], 0, 0, 0);
    }
    __syncthreads();
  }
  // ---- fused epilogue ----
  const int tloc = bm0 & 2047;
  const int bb = bm0 >> 11;
  if (bx < 10) {
    const int isq = (bx < 8);
    const int head = isq ? (2 * bx + wc) : (2 * (bx - 8) + wc);
    u16* outp = isq ? Qb : Kb;
    const size_t hbase = ((size_t)(bb * (isq ? 16 : 4) + head) * 2048) * 64;
    const int odd = la & 1;
#pragma unroll
    for (int m = 0; m < 2; ++m)
#pragma unroll
      for (int j = 0; j < 4; ++j) {
        const int tr = tloc + wr * 32 + m * 16 + hi * 4 + j;
        const float2* tb = tab + tr * 32 + (la >> 1);
        float y[4], ssl = 0.f;
#pragma unroll
        for (int n = 0; n < 4; ++n) {
          float v = acc[m][n][j];
          float p = __shfl_xor(v, 1);
          float2 cs = tb[n * 8];
          y[n] = odd ? fmaf(v, cs.x, p * cs.y)
                     : fmaf(v, cs.x, -p * cs.y);
          ssl = fmaf(y[n], y[n], ssl);
        }
        ssl += __shfl_xor(ssl, 1);
        ssl += __shfl_xor(ssl, 2);
        ssl += __shfl_xor(ssl, 4);
        ssl += __shfl_xor(ssl, 8);
        const float sc = rsqrtf(ssl * (1.0f / 64.0f) + 1e-6f);
        u16* rp = outp + hbase + (size_t)tr * 64 + la;
#pragma unroll
        for (int n = 0; n < 4; ++n) rp[n * 16] = f2b(y[n] * sc);
      }
  } else {
    // V block: bf16 into vbuf[64][132] (reuses lA/lB), transposed write
    u16* vbuf = smem;
#pragma unroll
    for (int m = 0; m < 2; ++m)
#pragma unroll
      for (int n = 0; n < 4; ++n)
#pragma unroll
        for (int j = 0; j < 4; ++j)
          vbuf[(wr * 32 + m * 16 + hi * 4 + j) * 132 + wc * 64 + n * 16 + la] =
              f2b(acc[m][n][j]);
    __syncthreads();
    const int dloc = tid >> 1, th = tid & 1;
    const int g = 2 * (bx - 10) + (dloc >> 6);
    const int d = dloc & 63;
    u16* dst = Vtb + ((size_t)(bb * 4 + g) * 64 + d) * 2048 + tloc + th * 32;
#pragma unroll
    for (int c = 0; c < 4; ++c) {
      u16x8 o;
#pragma unroll
      for (int e = 0; e < 8; ++e) o[e] = vbuf[(th * 32 + c * 8 + e) * 132 + dloc];
      *(u16x8*)(dst + c * 8) = o;
    }
  }
}

// ---- GEMM2: C[M,N] f32 = A[M,K](bf16) * Bt[N,K](bf16) ----
template<int OUT_BF16>
__global__ __launch_bounds__(256) void k_gemm_bt(const u16* __restrict__ A,
                                                 const u16* __restrict__ Bt,
                                                 void* __restrict__ Cv,
                                                 int M, int N, int K) {
  __shared__ u16 lA[64 * 64];
  __shared__ u16 lB[128 * 64];
  const int tid = threadIdx.x;
  const int lane = tid & 63, w = tid >> 6;
  const int wr = w >> 1, wc = w & 1;
  const int la = lane & 15, hi = lane >> 4;
  const int bm0 = blockIdx.y * 64, bn0 = blockIdx.x * 128;
  const f32x4 zero = {0.f, 0.f, 0.f, 0.f};
  f32x4 acc[2][4];
#pragma unroll
  for (int m = 0; m < 2; ++m)
#pragma unroll
    for (int n = 0; n < 4; ++n) acc[m][n] = zero;

  const int r = tid >> 3;
  const int s = tid & 7;
  for (int k0 = 0; k0 < K; k0 += 64) {
#pragma unroll
    for (int rr = 0; rr < 2; ++rr) {
      int row = rr * 32 + r;
      gload16(A + (size_t)(bm0 + row) * K + k0 + ((s ^ (row & 7)) << 3),
              &lA[(rr * 256 + tid) * 8]);
    }
#pragma unroll
    for (int rr = 0; rr < 4; ++rr) {
      int row = rr * 32 + r;
      gload16(Bt + (size_t)(bn0 + row) * K + k0 + ((s ^ (row & 7)) << 3),
              &lB[(rr * 256 + tid) * 8]);
    }
    __syncthreads();
#pragma unroll
    for (int kk = 0; kk < 2; ++kk) {
      bf16x8 af[2], bfr[4];
#pragma unroll
      for (int m = 0; m < 2; ++m) {
        int R = wr * 32 + m * 16 + la;
        af[m] = *(const bf16x8*)&lA[R * 64 + (((kk * 4 + hi) ^ (R & 7)) << 3)];
      }
#pragma unroll
      for (int n = 0; n < 4; ++n) {
        int R = wc * 64 + n * 16 + la;
        bfr[n] = *(const bf16x8*)&lB[R * 64 + (((kk * 4 + hi) ^ (R & 7)) << 3)];
      }
#pragma unroll
      for (int m = 0; m < 2; ++m)
#pragma unroll
        for (int n = 0; n < 4; ++n)
          acc[m][n] = __builtin_amdgcn_mfma_f32_16x16x32_bf16(af[m], bfr[n], acc[m][n], 0, 0, 0);
    }
    __syncthreads();
  }
  float* Cf = (float*)Cv;
  u16*   Cb = (u16*)Cv;
#pragma unroll
  for (int m = 0; m < 2; ++m)
#pragma unroll
    for (int n = 0; n < 4; ++n)
#pragma unroll
      for (int j = 0; j < 4; ++j) {
        int row = bm0 + wr * 32 + m * 16 + hi * 4 + j;
        int col = bn0 + wc * 64 + n * 16 + la;
        float v = acc[m][n][j];
        if (OUT_BF16) Cb[(size_t)row * N + col] = f2b(v);
        else          Cf[(size_t)row * N + col] = v;
      }
}

// ---- causal GQA flash attention, v9: v7 core + uniform sequential pairs ----
// grid (32 bh, 16), block 256 (4 waves x 16 q-rows). Each block processes
// qtileA = 31-y (nt 32-y) then qtileB = y (nt y+1): uniform 33 tile-iters
// per block, 512 blocks = 2/CU, constant 8 waves/CU, no drain tail.
// Double-buffer parity carries across the phase boundary (phase A's last
// iter prefetches phase B's tile 0). Inner body identical to v7.
__global__ __launch_bounds__(256, 2) void k_attn(const u16* __restrict__ Qb,
                                                 const u16* __restrict__ Kb,
                                                 const u16* __restrict__ Vtb,
                                                 u16* __restrict__ Ob) {
  __shared__ u16 lK[2][64][64];
  __shared__ u16 lVt[2][64][64];
  __shared__ u16 lP[4][16][64];
  const int bh = blockIdx.x;
  const int b = bh >> 4, h = bh & 15, g = h >> 2;
  const int y = blockIdx.y;
  const int qtileA = 31 - y, ntA = 32 - y;   // heavy phase
  const int qtileB = y,      ntB = y + 1;    // light phase
  const int tid = threadIdx.x;
  const int lane = tid & 63, w = tid >> 6;
  const int la = lane & 15, hi = lane >> 4;

  const u16* Qg  = Qb  + (size_t)(b * 16 + h) * 2048 * 64;
  const u16* Kg  = Kb  + (size_t)(b * 4 + g) * 2048 * 64;
  const u16* Vtg = Vtb + (size_t)(b * 4 + g) * 64 * 2048;

  bf16x8 qfA0, qfA1, qfB0, qfB1;
  {
    const u16* pA = Qg + (size_t)(qtileA * 64 + w * 16 + la) * 64 + hi * 8;
    qfA0 = *(const bf16x8*)pA;
    qfA1 = *(const bf16x8*)(pA + 32);
    const u16* pB = Qg + (size_t)(qtileB * 64 + w * 16 + la) * 64 + hi * 8;
    qfB0 = *(const bf16x8*)pB;
    qfB1 = *(const bf16x8*)(pB + 32);
  }
  const float C = 0.18033688011f;      // 0.125 * log2(e)
  const float nmc = -64.0f * C;        // fixed max (|q|=|k|=8 after RMS)
  float lA_ = 0.f, lB_ = 0.f;
  const f32x4 zero = {0.f, 0.f, 0.f, 0.f};
  f32x4 aoA[4], aoB[4];
#pragma unroll
  for (int f = 0; f < 4; ++f) { aoA[f] = zero; aoB[f] = zero; }

  const int sr = tid >> 3;             // staging row 0..31 (and +32)
  const int ss = (tid & 7) * 8;
  const int sw = ss ^ ((sr & 7) << 3);
  const int rcc = (hi * 8) ^ ((la & 7) << 3);

  {                                    // prologue: stage tile 0 (phase A)
    u16x8 k0 = *(const u16x8*)(Kg  + (size_t)sr * 64 + ss);
    u16x8 k1 = *(const u16x8*)(Kg  + (size_t)(sr + 32) * 64 + ss);
    u16x8 q0 = *(const u16x8*)(Vtg + (size_t)sr * 2048 + ss);
    u16x8 q1 = *(const u16x8*)(Vtg + (size_t)(sr + 32) * 2048 + ss);
    *(u16x8*)(&lK[0][sr][sw])       = k0;
    *(u16x8*)(&lK[0][sr + 32][sw])  = k1;
    *(u16x8*)(&lVt[0][sr][sw])      = q0;
    *(u16x8*)(&lVt[0][sr + 32][sw]) = q1;
  }

  // -------- phase A: qtileA, tiles kv = kt*64, kt = 0..ntA-1 --------
  for (int kt = 0; kt < ntA; ++kt) {
    const int cur = kt & 1;
    __syncthreads();                   // buf[cur] ready
    // prefetch tile kt+1 (or phase B's tile 0 when kt == ntA-1)
    u16x8 kreg0, kreg1, vreg0, vreg1;
    {
      int kv = (kt + 1 < ntA) ? (kt + 1) * 64 : 0;
      kreg0 = *(const u16x8*)(Kg  + (size_t)(kv + sr) * 64 + ss);
      kreg1 = *(const u16x8*)(Kg  + (size_t)(kv + sr + 32) * 64 + ss);
      vreg0 = *(const u16x8*)(Vtg + (size_t)sr * 2048 + kv + ss);
      vreg1 = *(const u16x8*)(Vtg + (size_t)(sr + 32) * 2048 + kv + ss);
    }
    float z_[4][4];
    __builtin_amdgcn_s_setprio(1);
#pragma unroll
    for (int n = 0; n < 4; ++n) {
      const u16* kr = &lK[cur][n * 16 + la][0];
      bf16x8 kb0 = *(const bf16x8*)(kr + rcc);
      bf16x8 kb1 = *(const bf16x8*)(kr + (rcc ^ 32));
      f32x4 z = zero;
      z = __builtin_amdgcn_mfma_f32_16x16x32_bf16(kb0, qfA0, z, 0, 0, 0);
      z = __builtin_amdgcn_mfma_f32_16x16x32_bf16(kb1, qfA1, z, 0, 0, 0);
#pragma unroll
      for (int j = 0; j < 4; ++j) z_[n][j] = z[j];
    }
    __builtin_amdgcn_s_setprio(0);
    if (kt == ntA - 1) {               // diagonal tile (tile-local coords)
#pragma unroll
      for (int n = 0; n < 4; ++n)
#pragma unroll
        for (int j = 0; j < 4; ++j)
          if (n * 16 + hi * 4 + j > w * 16 + la) z_[n][j] = -3e38f;
    }
    float rs = 0.f;
#pragma unroll
    for (int n = 0; n < 4; ++n)
#pragma unroll
      for (int j = 0; j < 4; ++j) {
        float pe = __builtin_amdgcn_exp2f(fmaf(z_[n][j], C, nmc));
        z_[n][j] = pe;
        rs += pe;
      }
    lA_ += rs;
#pragma unroll
    for (int n = 0; n < 4; ++n) {
      unsigned w0, w1;
      asm("v_cvt_pk_bf16_f32 %0, %1, %2" : "=v"(w0) : "v"(z_[n][0]), "v"(z_[n][1]));
      asm("v_cvt_pk_bf16_f32 %0, %1, %2" : "=v"(w1) : "v"(z_[n][2]), "v"(z_[n][3]));
      uint2 pw; pw.x = w0; pw.y = w1;
      *(uint2*)(&lP[w][la][(n * 16 + hi * 4) ^ ((la & 7) << 3)]) = pw;
    }
    {
      const u16* pr = &lP[w][la][0];
      bf16x8 pa0 = *(const bf16x8*)(pr + rcc);
      bf16x8 pa1 = *(const bf16x8*)(pr + (rcc ^ 32));
      __builtin_amdgcn_s_setprio(1);
#pragma unroll
      for (int f = 0; f < 4; ++f) {
        const u16* vr = &lVt[cur][f * 16 + la][0];
        bf16x8 v0 = *(const bf16x8*)(vr + rcc);
        bf16x8 v1 = *(const bf16x8*)(vr + (rcc ^ 32));
        aoA[f] = __builtin_amdgcn_mfma_f32_16x16x32_bf16(pa0, v0, aoA[f], 0, 0, 0);
        aoA[f] = __builtin_amdgcn_mfma_f32_16x16x32_bf16(pa1, v1, aoA[f], 0, 0, 0);
      }
      __builtin_amdgcn_s_setprio(0);
    }
    {                                  // write prefetched tile (always: B follows)
      const int nxt = cur ^ 1;
      *(u16x8*)(&lK[nxt][sr][sw])       = kreg0;
      *(u16x8*)(&lK[nxt][sr + 32][sw])  = kreg1;
      *(u16x8*)(&lVt[nxt][sr][sw])      = vreg0;
      *(u16x8*)(&lVt[nxt][sr + 32][sw]) = vreg1;
    }
  }
  // epilogue A (register/global only; next barrier orders LDS)
  lA_ += __shfl_xor(lA_, 16, 64);
  lA_ += __shfl_xor(lA_, 32, 64);
  {
    float linv[4];
#pragma unroll
    for (int j = 0; j < 4; ++j) linv[j] = 1.0f / __shfl(lA_, 4 * hi + j, 64);
#pragma unroll
    for (int f = 0; f < 4; ++f)
#pragma unroll
      for (int j = 0; j < 4; ++j) {
        int row = qtileA * 64 + w * 16 + hi * 4 + j;
        Ob[((size_t)(b * 2048 + row)) * 1024 + h * 64 + f * 16 + la] =
            f2b(aoA[f][j] * linv[j]);
      }
  }

  // -------- phase B: qtileB, tiles kv = kt*64, parity continues --------
  for (int kt = 0; kt < ntB; ++kt) {
    const int cur = (ntA + kt) & 1;
    __syncthreads();                   // buf[cur] ready
    u16x8 kreg0, kreg1, vreg0, vreg1;
    if (kt + 1 < ntB) {
      int kv = (kt + 1) * 64;
      kreg0 = *(const u16x8*)(Kg  + (size_t)(kv + sr) * 64 + ss);
      kreg1 = *(const u16x8*)(Kg  + (size_t)(kv + sr + 32) * 64 + ss);
      vreg0 = *(const u16x8*)(Vtg + (size_t)sr * 2048 + kv + ss);
      vreg1 = *(const u16x8*)(Vtg + (size_t)(sr + 32) * 2048 + kv + ss);
    }
    float z_[4][4];
    __builtin_amdgcn_s_setprio(1);
#pragma unroll
    for (int n = 0; n < 4; ++n) {
      const u16* kr = &lK[cur][n * 16 + la][0];
      bf16x8 kb0 = *(const bf16x8*)(kr + rcc);
      bf16x8 kb1 = *(const bf16x8*)(kr + (rcc ^ 32));
      f32x4 z = zero;
      z = __builtin_amdgcn_mfma_f32_16x16x32_bf16(kb0, qfB0, z, 0, 0, 0);
      z = __builtin_amdgcn_mfma_f32_16x16x32_bf16(kb1, qfB1, z, 0, 0, 0);
#pragma unroll
      for (int j = 0; j < 4; ++j) z_[n][j] = z[j];
    }
    __builtin_amdgcn_s_setprio(0);
    if (kt == ntB - 1) {               // diagonal tile
#pragma unroll
      for (int n = 0; n < 4; ++n)
#pragma unroll
        for (int j = 0; j < 4; ++j)
          if (n * 16 + hi * 4 + j > w * 16 + la) z_[n][j] = -3e38f;
    }
    float rs = 0.f;
#pragma unroll
    for (int n = 0; n < 4; ++n)
#pragma unroll
      for (int j = 0; j < 4; ++j) {
        float pe = __builtin_amdgcn_exp2f(fmaf(z_[n][j], C, nmc));
        z_[n][j] = pe;
        rs += pe;
      }
    lB_ += rs;
#pragma unroll
    for (int n = 0; n < 4; ++n) {
      unsigned w0, w1;
      asm("v_cvt_pk_bf16_f32 %0, %1, %2" : "=v"(w0) : "v"(z_[n][0]), "v"(z_[n][1]));
      asm("v_cvt_pk_bf16_f32 %0, %1, %2" : "=v"(w1) : "v"(z_[n][2]), "v"(z_[n][3]));
      uint2 pw; pw.x = w0; pw.y = w1;
      *(uint2*)(&lP[w][la][(n * 16 + hi * 4) ^ ((la & 7) << 3)]) = pw;
    }
    {
      const u16* pr = &lP[w][la][0];
      bf16x8 pa0 = *(const bf16x8*)(pr + rcc);
      bf16x8 pa1 = *(const bf16x8*)(pr + (rcc ^ 32));
      __builtin_amdgcn_s_setprio(1);
#pragma unroll
      for (int f = 0; f < 4; ++f) {
        const u16* vr = &lVt[cur][f * 16 + la][0];
        bf16x8 v0 = *(const bf16x8*)(vr + rcc);
        bf16x8 v1 = *(const bf16x8*)(vr + (rcc ^ 32));
        aoB[f] = __builtin_amdgcn_mfma_f32_16x16x32_bf16(pa0, v0, aoB[f], 0, 0, 0);
        aoB[f] = __builtin_amdgcn_mfma_f32_16x16x32_bf16(pa1, v1, aoB[f], 0, 0, 0);
      }
      __builtin_amdgcn_s_setprio(0);
    }
    if (kt + 1 < ntB) {
      const int nxt = cur ^ 1;
      *(u16x8*)(&lK[nxt][sr][sw])       = kreg0;
      *(u16x8*)(&lK[nxt][sr + 32][sw])  = kreg1;
      *(u16x8*)(&lVt[nxt][sr][sw])      = vreg0;
      *(u16x8*)(&lVt[nxt][sr + 32][sw]) = vreg1;
    }
  }
  // epilogue B
  lB_ += __shfl_xor(lB_, 16, 64);
  lB_ += __shfl_xor(lB_, 32, 64);
  {
    float linv[4];
#pragma unroll
    for (int j = 0; j < 4; ++j) linv[j] = 1.0f / __shfl(lB_, 4 * hi + j, 64);
#pragma unroll
    for (int f = 0; f < 4; ++f)
#pragma unroll
      for (int j = 0; j < 4; ++j) {
        int row = qtileB * 64 + w * 16 + hi * 4 + j;
        Ob[((size_t)(b * 2048 + row)) * 1024 + h * 64 + f * 16 + la] =
            f2b(aoB[f][j] * linv[j]);
      }
  }
}

extern "C" void kernel_launch(void* const* d_in, const int* in_sizes, int n_in,
                              void* d_out, int out_size, void* d_ws, size_t ws_size,
                              hipStream_t stream) {
  const float* x  = (const float*)d_in[0];   // (2,2048,1024) f32
  const float* wa = (const float*)d_in[1];   // (1024,1536)  f32
  const float* wp = (const float*)d_in[2];   // (1024,1024)  f32
  float* out = (float*)d_out;                // (2,2048,1024) f32
  char* ws = (char*)d_ws;
  u16* xb    = (u16*)(ws + 0);          // 4096x1024 bf16
  u16* waT   = (u16*)(ws + 8388608);    // 1536x1024 bf16
  u16* wpT   = (u16*)(ws + 11534336);   // 1024x1024 bf16
  u16* Qb    = (u16*)(ws + 26214400);   // [2][16][2048][64] bf16
  u16* Kb    = (u16*)(ws + 34603008);   // [2][4][2048][64] bf16
  u16* Vtb   = (u16*)(ws + 36700160);   // [2][4][64][2048] bf16
  u16* Ob    = (u16*)(ws + 38797312);   // 4096x1024 bf16
  float2* rt = (float2*)(ws + 47185920); // 2048x32 float2 (512KB)

  k_prep<<<4864, 256, 0, stream>>>(x, wa, wp, xb, waT, wpT, rt);
  k_gemm1<<<dim3(12, 64), 256, 0, stream>>>(xb, waT, rt, Qb, Kb, Vtb);
  k_attn<<<dim3(32, 16), 256, 0, stream>>>(Qb, Kb, Vtb, Ob);
  k_gemm_bt<0><<<dim3(8, 64), 256, 0, stream>>>(Ob, wpT, out, 4096, 1024, 1024);
}

// Round 13
// 81.577 us; speedup vs baseline: 1.1222x; 1.0125x over previous
//
#include <hip/hip_runtime.h>

typedef unsigned short u16;
typedef __attribute__((ext_vector_type(8))) short bf16x8;
typedef __attribute__((ext_vector_type(4))) float f32x4;
typedef __attribute__((ext_vector_type(8))) unsigned short u16x8;
typedef __attribute__((ext_vector_type(4))) unsigned short u16x4;
typedef __attribute__((ext_vector_type(2))) unsigned short u16x2;

// ---- bf16 helpers (RNE) ----
__device__ __forceinline__ u16 f2b(float f) {
  unsigned u = __builtin_bit_cast(unsigned, f);
  unsigned r = (u + 0x7fffu + ((u >> 16) & 1u)) >> 16;
  return (u16)r;
}
__device__ __forceinline__ float b2f(u16 u) {
  return __builtin_bit_cast(float, ((unsigned)u) << 16);
}
__device__ __forceinline__ void gload16(const void* g, void* l) {
  __builtin_amdgcn_global_load_lds(
      (const __attribute__((address_space(1))) unsigned int*)g,
      (__attribute__((address_space(3))) unsigned int*)l, 16, 0, 0);
}

// ---- fused prep: x cast (2048) | waT (1536) | wpT (1024) | rope tab (256) ----
__global__ __launch_bounds__(256) void k_prep(const float* __restrict__ x,
                                              const float* __restrict__ wa,
                                              const float* __restrict__ wp,
                                              u16* __restrict__ xb,
                                              u16* __restrict__ waT,
                                              u16* __restrict__ wpT,
                                              float2* __restrict__ tab) {
  __shared__ float t[32][33];
  const int idx = blockIdx.x;
  const int tid = threadIdx.x;
  if (idx < 2048) {                       // cast x -> bf16, 8 elems/thread
    int i = idx * 256 + tid;
    float4 v0 = ((const float4*)x)[i * 2];
    float4 v1 = ((const float4*)x)[i * 2 + 1];
    u16x8 o;
    o[0] = f2b(v0.x); o[1] = f2b(v0.y); o[2] = f2b(v0.z); o[3] = f2b(v0.w);
    o[4] = f2b(v1.x); o[5] = f2b(v1.y); o[6] = f2b(v1.z); o[7] = f2b(v1.w);
    ((u16x8*)xb)[i] = o;
    return;
  }
  const int tx = tid & 31, ty = tid >> 5; // transpose tiles, block as (32,8)
  if (idx < 3584) {                       // waT: (1024 x 1536) -> (1536 x 1024)
    int tt = idx - 2048;
    int c0 = (tt % 48) * 32, r0 = (tt / 48) * 32;
    for (int ii = 0; ii < 4; ++ii)
      t[ty + ii * 8][tx] = wa[(size_t)(r0 + ty + ii * 8) * 1536 + c0 + tx];
    __syncthreads();
    for (int ii = 0; ii < 4; ++ii)
      waT[(size_t)(c0 + ty + ii * 8) * 1024 + r0 + tx] = f2b(t[tx][ty + ii * 8]);
    return;
  }
  if (idx < 4608) {                       // wpT: (1024 x 1024) -> (1024 x 1024)
    int tt = idx - 3584;
    int c0 = (tt & 31) * 32, r0 = (tt >> 5) * 32;
    for (int ii = 0; ii < 4; ++ii)
      t[ty + ii * 8][tx] = wp[(size_t)(r0 + ty + ii * 8) * 1024 + c0 + tx];
    __syncthreads();
    for (int ii = 0; ii < 4; ++ii)
      wpT[(size_t)(c0 + ty + ii * 8) * 1024 + r0 + tx] = f2b(t[tx][ty + ii * 8]);
    return;
  }
  {                                       // rope table
    int e = (idx - 4608) * 256 + tid;     // 65536 entries
    int tt = e >> 5, i = e & 31;
    float inv = expf((float)(2 * i) * -0.14391156831f);
    float fr = (float)tt * inv;
    float s, c;
    sincosf(fr, &s, &c);
    tab[tt * 32 + i] = make_float2(c, s);
  }
}

// ---- GEMM1 + fused rope/rms/V-transpose epilogue ----
__global__ __launch_bounds__(256) void k_gemm1(const u16* __restrict__ A,
                                               const u16* __restrict__ Bt,
                                               const float2* __restrict__ tab,
                                               u16* __restrict__ Qb,
                                               u16* __restrict__ Kb,
                                               u16* __restrict__ Vtb) {
  __shared__ u16 smem[64 * 64 + 128 * 64];   // lA | lB; reused as vbuf
  u16* lA = smem;
  u16* lB = smem + 64 * 64;
  const int tid = threadIdx.x;
  const int lane = tid & 63, w = tid >> 6;
  const int wr = w >> 1, wc = w & 1;
  const int la = lane & 15, hi = lane >> 4;
  const int bx = blockIdx.x;
  const int bm0 = blockIdx.y * 64, bn0 = bx * 128;
  const int K = 1024;
  const f32x4 zero = {0.f, 0.f, 0.f, 0.f};
  f32x4 acc[2][4];
#pragma unroll
  for (int m = 0; m < 2; ++m)
#pragma unroll
    for (int n = 0; n < 4; ++n) acc[m][n] = zero;

  const int r = tid >> 3;
  const int s = tid & 7;
  for (int k0 = 0; k0 < K; k0 += 64) {
#pragma unroll
    for (int rr = 0; rr < 2; ++rr) {
      int row = rr * 32 + r;
      gload16(A + (size_t)(bm0 + row) * K + k0 + ((s ^ (row & 7)) << 3),
              &lA[(rr * 256 + tid) * 8]);
    }
#pragma unroll
    for (int rr = 0; rr < 4; ++rr) {
      int row = rr * 32 + r;
      gload16(Bt + (size_t)(bn0 + row) * K + k0 + ((s ^ (row & 7)) << 3),
              &lB[(rr * 256 + tid) * 8]);
    }
    __syncthreads();
#pragma unroll
    for (int kk = 0; kk < 2; ++kk) {
      bf16x8 af[2], bfr[4];
#pragma unroll
      for (int m = 0; m < 2; ++m) {
        int R = wr * 32 + m * 16 + la;
        af[m] = *(const bf16x8*)&lA[R * 64 + (((kk * 4 + hi) ^ (R & 7)) << 3)];
      }
#pragma unroll
      for (int n = 0; n < 4; ++n) {
        int R = wc * 64 + n * 16 + la;
        bfr[n] = *(const bf16x8*)&lB[R * 64 + (((kk * 4 + hi) ^ (R & 7)) << 3)];
      }
#pragma unroll
      for (int m = 0; m < 2; ++m)
#pragma unroll
        for (int n = 0; n < 4; ++n)
          acc[m][n] = __builtin_amdgcn_mfma_f32_16x16x32_bf16(af[m], bfr[n], acc[m][n], 0, 0, 0);
    }
    __syncthreads();
  }
  // ---- fused epilogue ----
  const int tloc = bm0 & 2047;
  const int bb = bm0 >> 11;
  if (bx < 10) {
    const int isq = (bx < 8);
    const int head = isq ? (2 * bx + wc) : (2 * (bx - 8) + wc);
    u16* outp = isq ? Qb : Kb;
    const size_t hbase = ((size_t)(bb * (isq ? 16 : 4) + head) * 2048) * 64;
    const int odd = la & 1;
#pragma unroll
    for (int m = 0; m < 2; ++m)
#pragma unroll
      for (int j = 0; j < 4; ++j) {
        const int tr = tloc + wr * 32 + m * 16 + hi * 4 + j;
        const float2* tb = tab + tr * 32 + (la >> 1);
        float y[4], ssl = 0.f;
#pragma unroll
        for (int n = 0; n < 4; ++n) {
          float v = acc[m][n][j];
          float p = __shfl_xor(v, 1);
          float2 cs = tb[n * 8];
          y[n] = odd ? fmaf(v, cs.x, p * cs.y)
                     : fmaf(v, cs.x, -p * cs.y);
          ssl = fmaf(y[n], y[n], ssl);
        }
        ssl += __shfl_xor(ssl, 1);
        ssl += __shfl_xor(ssl, 2);
        ssl += __shfl_xor(ssl, 4);
        ssl += __shfl_xor(ssl, 8);
        const float sc = rsqrtf(ssl * (1.0f / 64.0f) + 1e-6f);
        u16* rp = outp + hbase + (size_t)tr * 64 + la;
#pragma unroll
        for (int n = 0; n < 4; ++n) rp[n * 16] = f2b(y[n] * sc);
      }
  } else {
    // V block: bf16 into vbuf[64][132] (reuses lA/lB), transposed write
    u16* vbuf = smem;
#pragma unroll
    for (int m = 0; m < 2; ++m)
#pragma unroll
      for (int n = 0; n < 4; ++n)
#pragma unroll
        for (int j = 0; j < 4; ++j)
          vbuf[(wr * 32 + m * 16 + hi * 4 + j) * 132 + wc * 64 + n * 16 + la] =
              f2b(acc[m][n][j]);
    __syncthreads();
    const int dloc = tid >> 1, th = tid & 1;
    const int g = 2 * (bx - 10) + (dloc >> 6);
    const int d = dloc & 63;
    u16* dst = Vtb + ((size_t)(bb * 4 + g) * 64 + d) * 2048 + tloc + th * 32;
#pragma unroll
    for (int c = 0; c < 4; ++c) {
      u16x8 o;
#pragma unroll
      for (int e = 0; e < 8; ++e) o[e] = vbuf[(th * 32 + c * 8 + e) * 132 + dloc];
      *(u16x8*)(dst + c * 8) = o;
    }
  }
}

// ---- GEMM2: C[M,N] f32 = A[M,K](bf16) * Bt[N,K](bf16) ----
template<int OUT_BF16>
__global__ __launch_bounds__(256) void k_gemm_bt(const u16* __restrict__ A,
                                                 const u16* __restrict__ Bt,
                                                 void* __restrict__ Cv,
                                                 int M, int N, int K) {
  __shared__ u16 lA[64 * 64];
  __shared__ u16 lB[128 * 64];
  const int tid = threadIdx.x;
  const int lane = tid & 63, w = tid >> 6;
  const int wr = w >> 1, wc = w & 1;
  const int la = lane & 15, hi = lane >> 4;
  const int bm0 = blockIdx.y * 64, bn0 = blockIdx.x * 128;
  const f32x4 zero = {0.f, 0.f, 0.f, 0.f};
  f32x4 acc[2][4];
#pragma unroll
  for (int m = 0; m < 2; ++m)
#pragma unroll
    for (int n = 0; n < 4; ++n) acc[m][n] = zero;

  const int r = tid >> 3;
  const int s = tid & 7;
  for (int k0 = 0; k0 < K; k0 += 64) {
#pragma unroll
    for (int rr = 0; rr < 2; ++rr) {
      int row = rr * 32 + r;
      gload16(A + (size_t)(bm0 + row) * K + k0 + ((s ^ (row & 7)) << 3),
              &lA[(rr * 256 + tid) * 8]);
    }
#pragma unroll
    for (int rr = 0; rr < 4; ++rr) {
      int row = rr * 32 + r;
      gload16(Bt + (size_t)(bn0 + row) * K + k0 + ((s ^ (row & 7)) << 3),
              &lB[(rr * 256 + tid) * 8]);
    }
    __syncthreads();
#pragma unroll
    for (int kk = 0; kk < 2; ++kk) {
      bf16x8 af[2], bfr[4];
#pragma unroll
      for (int m = 0; m < 2; ++m) {
        int R = wr * 32 + m * 16 + la;
        af[m] = *(const bf16x8*)&lA[R * 64 + (((kk * 4 + hi) ^ (R & 7)) << 3)];
      }
#pragma unroll
      for (int n = 0; n < 4; ++n) {
        int R = wc * 64 + n * 16 + la;
        bfr[n] = *(const bf16x8*)&lB[R * 64 + (((kk * 4 + hi) ^ (R & 7)) << 3)];
      }
#pragma unroll
      for (int m = 0; m < 2; ++m)
#pragma unroll
        for (int n = 0; n < 4; ++n)
          acc[m][n] = __builtin_amdgcn_mfma_f32_16x16x32_bf16(af[m], bfr[n], acc[m][n], 0, 0, 0);
    }
    __syncthreads();
  }
  float* Cf = (float*)Cv;
  u16*   Cb = (u16*)Cv;
#pragma unroll
  for (int m = 0; m < 2; ++m)
#pragma unroll
    for (int n = 0; n < 4; ++n)
#pragma unroll
      for (int j = 0; j < 4; ++j) {
        int row = bm0 + wr * 32 + m * 16 + hi * 4 + j;
        int col = bn0 + wc * 64 + n * 16 + la;
        float v = acc[m][n][j];
        if (OUT_BF16) Cb[(size_t)row * N + col] = f2b(v);
        else          Cf[(size_t)row * N + col] = v;
      }
}

// ---- causal GQA flash attention, v10: joint qtile pairs ----
// grid (32 bh, 16), block 256 (4 waves x 16 q-rows). Each block owns TWO
// qtiles processed in ONE kv loop: A = heavy, B = light with B's tile
// range a PREFIX of A's. Per round: shared K/V fragments (LDS->reg once),
// QK+softmax+PV for A always, for B while kt <= qtB. Rounds/block = qtA+1;
// zig-zag map makes per-CU block pairs (y, y+8) sum to 49 rounds.
__global__ __launch_bounds__(256, 2) void k_attn(const u16* __restrict__ Qb,
                                                 const u16* __restrict__ Kb,
                                                 const u16* __restrict__ Vtb,
                                                 u16* __restrict__ Ob) {
  __shared__ u16 lK[2][64][64];
  __shared__ u16 lVt[2][64][64];
  __shared__ u16 lP[4][16][64];
  const int bh = blockIdx.x;
  const int b = bh >> 4, h = bh & 15, g = h >> 2;
  const int y = blockIdx.y;
  int qtA, qtB;
  if (y < 8) { qtA = 31 - y; qtB = y; }
  else       { qtA = y + 8;  qtB = 23 - y; }
  const int ntA = qtA + 1;
  const int tid = threadIdx.x;
  const int lane = tid & 63, w = tid >> 6;
  const int la = lane & 15, hi = lane >> 4;

  const u16* Qg  = Qb  + (size_t)(b * 16 + h) * 2048 * 64;
  const u16* Kg  = Kb  + (size_t)(b * 4 + g) * 2048 * 64;
  const u16* Vtg = Vtb + (size_t)(b * 4 + g) * 64 * 2048;

  bf16x8 qfA0, qfA1, qfB0, qfB1;
  {
    const u16* pA = Qg + (size_t)(qtA * 64 + w * 16 + la) * 64 + hi * 8;
    qfA0 = *(const bf16x8*)pA;
    qfA1 = *(const bf16x8*)(pA + 32);
    const u16* pB = Qg + (size_t)(qtB * 64 + w * 16 + la) * 64 + hi * 8;
    qfB0 = *(const bf16x8*)pB;
    qfB1 = *(const bf16x8*)(pB + 32);
  }
  const float C = 0.18033688011f;      // 0.125 * log2(e)
  const float nmc = -64.0f * C;        // fixed max (|q|=|k|=8 after RMS)
  float lA_ = 0.f, lB_ = 0.f;
  const f32x4 zero = {0.f, 0.f, 0.f, 0.f};
  f32x4 aoA[4], aoB[4];
#pragma unroll
  for (int f = 0; f < 4; ++f) { aoA[f] = zero; aoB[f] = zero; }

  const int sr = tid >> 3;             // staging row 0..31 (and +32)
  const int ss = (tid & 7) * 8;
  const int sw = ss ^ ((sr & 7) << 3);
  const int rcc = (hi * 8) ^ ((la & 7) << 3);

  {                                    // prologue: stage tile 0
    u16x8 k0 = *(const u16x8*)(Kg  + (size_t)sr * 64 + ss);
    u16x8 k1 = *(const u16x8*)(Kg  + (size_t)(sr + 32) * 64 + ss);
    u16x8 q0 = *(const u16x8*)(Vtg + (size_t)sr * 2048 + ss);
    u16x8 q1 = *(const u16x8*)(Vtg + (size_t)(sr + 32) * 2048 + ss);
    *(u16x8*)(&lK[0][sr][sw])       = k0;
    *(u16x8*)(&lK[0][sr + 32][sw])  = k1;
    *(u16x8*)(&lVt[0][sr][sw])      = q0;
    *(u16x8*)(&lVt[0][sr + 32][sw]) = q1;
  }

  for (int kt = 0; kt < ntA; ++kt) {
    const int cur = kt & 1;
    __syncthreads();                   // buf[cur] ready (written last iter)

    // prefetch next tile (issued after barrier; drains at trailing ds_write)
    u16x8 kreg0, kreg1, vreg0, vreg1;
    if (kt + 1 < ntA) {
      int kv = (kt + 1) * 64;
      kreg0 = *(const u16x8*)(Kg  + (size_t)(kv + sr) * 64 + ss);
      kreg1 = *(const u16x8*)(Kg  + (size_t)(kv + sr + 32) * 64 + ss);
      vreg0 = *(const u16x8*)(Vtg + (size_t)sr * 2048 + kv + ss);
      vreg1 = *(const u16x8*)(Vtg + (size_t)(sr + 32) * 2048 + kv + ss);
    }

    // K and V fragments: LDS -> registers ONCE, shared by A and B
    bf16x8 kb[4][2], vb[4][2];
#pragma unroll
    for (int n = 0; n < 4; ++n) {
      const u16* kr = &lK[cur][n * 16 + la][0];
      kb[n][0] = *(const bf16x8*)(kr + rcc);
      kb[n][1] = *(const bf16x8*)(kr + (rcc ^ 32));
      const u16* vr = &lVt[cur][n * 16 + la][0];
      vb[n][0] = *(const bf16x8*)(vr + rcc);
      vb[n][1] = *(const bf16x8*)(vr + (rcc ^ 32));
    }

    // ---------------- qtile A ----------------
    {
      float z_[4][4];
      __builtin_amdgcn_s_setprio(1);
#pragma unroll
      for (int n = 0; n < 4; ++n) {
        f32x4 z = zero;
        z = __builtin_amdgcn_mfma_f32_16x16x32_bf16(kb[n][0], qfA0, z, 0, 0, 0);
        z = __builtin_amdgcn_mfma_f32_16x16x32_bf16(kb[n][1], qfA1, z, 0, 0, 0);
#pragma unroll
        for (int j = 0; j < 4; ++j) z_[n][j] = z[j];
      }
      __builtin_amdgcn_s_setprio(0);
      if (kt == qtA) {                 // diagonal (tile-local coords)
#pragma unroll
        for (int n = 0; n < 4; ++n)
#pragma unroll
          for (int j = 0; j < 4; ++j)
            if (n * 16 + hi * 4 + j > w * 16 + la) z_[n][j] = -3e38f;
      }
      float rs = 0.f;
#pragma unroll
      for (int n = 0; n < 4; ++n)
#pragma unroll
        for (int j = 0; j < 4; ++j) {
          float pe = __builtin_amdgcn_exp2f(fmaf(z_[n][j], C, nmc));
          z_[n][j] = pe;
          rs += pe;
        }
      lA_ += rs;
#pragma unroll
      for (int n = 0; n < 4; ++n) {
        unsigned w0, w1;
        asm("v_cvt_pk_bf16_f32 %0, %1, %2" : "=v"(w0) : "v"(z_[n][0]), "v"(z_[n][1]));
        asm("v_cvt_pk_bf16_f32 %0, %1, %2" : "=v"(w1) : "v"(z_[n][2]), "v"(z_[n][3]));
        uint2 pw; pw.x = w0; pw.y = w1;
        *(uint2*)(&lP[w][la][(n * 16 + hi * 4) ^ ((la & 7) << 3)]) = pw;
      }
      const u16* pr = &lP[w][la][0];
      bf16x8 pa0 = *(const bf16x8*)(pr + rcc);
      bf16x8 pa1 = *(const bf16x8*)(pr + (rcc ^ 32));
      __builtin_amdgcn_s_setprio(1);
#pragma unroll
      for (int f = 0; f < 4; ++f) {
        aoA[f] = __builtin_amdgcn_mfma_f32_16x16x32_bf16(pa0, vb[f][0], aoA[f], 0, 0, 0);
        aoA[f] = __builtin_amdgcn_mfma_f32_16x16x32_bf16(pa1, vb[f][1], aoA[f], 0, 0, 0);
      }
      __builtin_amdgcn_s_setprio(0);
    }

    // ---------------- qtile B (prefix of A's range) ----------------
    if (kt <= qtB) {
      float z_[4][4];
      __builtin_amdgcn_s_setprio(1);
#pragma unroll
      for (int n = 0; n < 4; ++n) {
        f32x4 z = zero;
        z = __builtin_amdgcn_mfma_f32_16x16x32_bf16(kb[n][0], qfB0, z, 0, 0, 0);
        z = __builtin_amdgcn_mfma_f32_16x16x32_bf16(kb[n][1], qfB1, z, 0, 0, 0);
#pragma unroll
        for (int j = 0; j < 4; ++j) z_[n][j] = z[j];
      }
      __builtin_amdgcn_s_setprio(0);
      if (kt == qtB) {                 // diagonal
#pragma unroll
        for (int n = 0; n < 4; ++n)
#pragma unroll
          for (int j = 0; j < 4; ++j)
            if (n * 16 + hi * 4 + j > w * 16 + la) z_[n][j] = -3e38f;
      }
      float rs = 0.f;
#pragma unroll
      for (int n = 0; n < 4; ++n)
#pragma unroll
        for (int j = 0; j < 4; ++j) {
          float pe = __builtin_amdgcn_exp2f(fmaf(z_[n][j], C, nmc));
          z_[n][j] = pe;
          rs += pe;
        }
      lB_ += rs;
#pragma unroll
      for (int n = 0; n < 4; ++n) {
        unsigned w0, w1;
        asm("v_cvt_pk_bf16_f32 %0, %1, %2" : "=v"(w0) : "v"(z_[n][0]), "v"(z_[n][1]));
        asm("v_cvt_pk_bf16_f32 %0, %1, %2" : "=v"(w1) : "v"(z_[n][2]), "v"(z_[n][3]));
        uint2 pw; pw.x = w0; pw.y = w1;
        *(uint2*)(&lP[w][la][(n * 16 + hi * 4) ^ ((la & 7) << 3)]) = pw;
      }
      const u16* pr = &lP[w][la][0];
      bf16x8 pa0 = *(const bf16x8*)(pr + rcc);
      bf16x8 pa1 = *(const bf16x8*)(pr + (rcc ^ 32));
      __builtin_amdgcn_s_setprio(1);
#pragma unroll
      for (int f = 0; f < 4; ++f) {
        aoB[f] = __builtin_amdgcn_mfma_f32_16x16x32_bf16(pa0, vb[f][0], aoB[f], 0, 0, 0);
        aoB[f] = __builtin_amdgcn_mfma_f32_16x16x32_bf16(pa1, vb[f][1], aoB[f], 0, 0, 0);
      }
      __builtin_amdgcn_s_setprio(0);
    }

    if (kt + 1 < ntA) {                // write next tile into other buffer
      const int nxt = cur ^ 1;
      *(u16x8*)(&lK[nxt][sr][sw])       = kreg0;
      *(u16x8*)(&lK[nxt][sr + 32][sw])  = kreg1;
      *(u16x8*)(&lVt[nxt][sr][sw])      = vreg0;
      *(u16x8*)(&lVt[nxt][sr + 32][sw]) = vreg1;
    }
  }

  // epilogues: reduce l across hi-copies once, normalize, store
  lA_ += __shfl_xor(lA_, 16, 64);
  lA_ += __shfl_xor(lA_, 32, 64);
  lB_ += __shfl_xor(lB_, 16, 64);
  lB_ += __shfl_xor(lB_, 32, 64);
  {
    float linv[4];
#pragma unroll
    for (int j = 0; j < 4; ++j) linv[j] = 1.0f / __shfl(lA_, 4 * hi + j, 64);
#pragma unroll
    for (int f = 0; f < 4; ++f)
#pragma unroll
      for (int j = 0; j < 4; ++j) {
        int row = qtA * 64 + w * 16 + hi * 4 + j;
        Ob[((size_t)(b * 2048 + row)) * 1024 + h * 64 + f * 16 + la] =
            f2b(aoA[f][j] * linv[j]);
      }
  }
  {
    float linv[4];
#pragma unroll
    for (int j = 0; j < 4; ++j) linv[j] = 1.0f / __shfl(lB_, 4 * hi + j, 64);
#pragma unroll
    for (int f = 0; f < 4; ++f)
#pragma unroll
      for (int j = 0; j < 4; ++j) {
        int row = qtB * 64 + w * 16 + hi * 4 + j;
        Ob[((size_t)(b * 2048 + row)) * 1024 + h * 64 + f * 16 + la] =
            f2b(aoB[f][j] * linv[j]);
      }
  }
}

extern "C" void kernel_launch(void* const* d_in, const int* in_sizes, int n_in,
                              void* d_out, int out_size, void* d_ws, size_t ws_size,
                              hipStream_t stream) {
  const float* x  = (const float*)d_in[0];   // (2,2048,1024) f32
  const float* wa = (const float*)d_in[1];   // (1024,1536)  f32
  const float* wp = (const float*)d_in[2];   // (1024,1024)  f32
  float* out = (float*)d_out;                // (2,2048,1024) f32
  char* ws = (char*)d_ws;
  u16* xb    = (u16*)(ws + 0);          // 4096x1024 bf16
  u16* waT   = (u16*)(ws + 8388608);    // 1536x1024 bf16
  u16* wpT   = (u16*)(ws + 11534336);   // 1024x1024 bf16
  u16* Qb    = (u16*)(ws + 26214400);   // [2][16][2048][64] bf16
  u16* Kb    = (u16*)(ws + 34603008);   // [2][4][2048][64] bf16
  u16* Vtb   = (u16*)(ws + 36700160);   // [2][4][64][2048] bf16
  u16* Ob    = (u16*)(ws + 38797312);   // 4096x1024 bf16
  float2* rt = (float2*)(ws + 47185920); // 2048x32 float2 (512KB)

  k_prep<<<4864, 256, 0, stream>>>(x, wa, wp, xb, waT, wpT, rt);
  k_gemm1<<<dim3(12, 64), 256, 0, stream>>>(xb, waT, rt, Qb, Kb, Vtb);
  k_attn<<<dim3(32, 16), 256, 0, stream>>>(Qb, Kb, Vtb, Ob);
  k_gemm_bt<0><<<dim3(8, 64), 256, 0, stream>>>(Ob, wpT, out, 4096, 1024, 1024);
}